// Round 17
// baseline (527.674 us; speedup 1.0000x reference)
//
#include <hip/hip_runtime.h>
#include <hip/hip_bf16.h>

// Problem constants
#define NB 8
#define NSP 16384      // 128*128

typedef unsigned short u16;
typedef __attribute__((ext_vector_type(8))) short short8_;
typedef __attribute__((ext_vector_type(8))) unsigned short u16x8;
typedef __attribute__((ext_vector_type(4))) float f32x4;
typedef __attribute__((ext_vector_type(4))) unsigned u32x4;
typedef __attribute__((ext_vector_type(2))) _Float16 h16x2;

__device__ __forceinline__ float b2f(u16 u) {
  unsigned v = ((unsigned)u) << 16;
  float f;
  __builtin_memcpy(&f, &v, 4);
  return f;
}
__device__ __forceinline__ u16 f2b(float f) {
  __hip_bfloat16 h = __float2bfloat16(f);  // RNE
  u16 u;
  __builtin_memcpy(&u, &h, 2);
  return u;
}
__device__ __forceinline__ u16 f2h(float f) {
  _Float16 h = (_Float16)f;                // RNE
  u16 u;
  __builtin_memcpy(&u, &h, 2);
  return u;
}
__device__ __forceinline__ float ldf(const void* p, size_t i, int isbf) {
  return isbf ? b2f(((const u16*)p)[i]) : ((const float*)p)[i];
}
// v_dot2_f32_f16: a.x*b.x + a.y*b.y + c
__device__ __forceinline__ float fdot2u(unsigned a, unsigned b, float c) {
  h16x2 x, y;
  __builtin_memcpy(&x, &a, 4);
  __builtin_memcpy(&y, &b, 4);
  return __builtin_amdgcn_fdot2(x, y, c, false);
}

// ---------------------------------------------------------------------------
// prep_all: ONE launch. Blocks:
//   0- 71: zero S/qs/ks + flag
//  72-143: fragment-order w_q/w_k/w_qkv (3 mats x 24)
// 144-335: bf16 copy w_v
// 336-491: dw weights -> PACKED fp16-PAIR table Wdwp[384][104] u32:
//   per channel: wA2[7][4]@0 wB2[7][4]@28 wA1[5][3]@56 wB1[5][3]@71
//                wA0[3][2]@86 wB0[3][2]@92  (98..103 zero)
//   A-pairs: {w0,w1},{w2,w3},...,pad0  B-pairs: {0,w0},{w1,w2},...
// ---------------------------------------------------------------------------
__global__ __launch_bounds__(256) void prep_all(
    const void* __restrict__ wq, const void* __restrict__ wk,
    const void* __restrict__ wqkv, const void* __restrict__ wv,
    const void* __restrict__ wdw3, const void* __restrict__ wdw5,
    const void* __restrict__ wdw7, const void* __restrict__ temp,
    u16* __restrict__ Wqf, u16* __restrict__ Wkf, u16* __restrict__ Wkvf,
    u16* __restrict__ Wbv, unsigned* __restrict__ Wdwp,
    int* __restrict__ flag, float* __restrict__ Sz)
{
  const int isbf = (((const u16*)temp)[0] != 0) ? 1 : 0;
  const int bx = blockIdx.x;
  const int tid = threadIdx.x;

  if (bx < 72) {
    int i = bx * 256 + tid;
    if (i == 0) *flag = isbf;
    if (i < 18432) Sz[i] = 0.f;
  } else if (bx < 144) {
    const int mb = bx - 72;
    const int mat = mb / 24;
    const int fi = (mb - mat * 24) * 256 + tid;   // 0..6143
    const int lane = fi & 63, m = (fi >> 6) & 7, ks = (fi >> 9) & 3, blk = fi >> 11;
    const int quad = lane >> 4, col = lane & 15;
    const void* src;
    u16* dst;
    size_t so;
    if (mat == 2) {
      so = (size_t)(blk * 128 + m * 16 + col) * 128 + ks * 32 + quad * 8;
      src = wqkv; dst = Wkvf;
    } else {
      so = (size_t)(m * 16 + col) * 384 + blk * 128 + ks * 32 + quad * 8;
      src = mat ? wk : wq; dst = mat ? Wkf : Wqf;
    }
    if (isbf) {
      *(u16x8*)&dst[(size_t)fi * 8] = *(const u16x8*)((const u16*)src + so);
    } else {
      f32x4 a = *(const f32x4*)((const float*)src + so);
      f32x4 b = *(const f32x4*)((const float*)src + so + 4);
      u16 us[8];
#pragma unroll
      for (int j = 0; j < 4; j++) { us[j] = f2b(a[j]); us[4 + j] = f2b(b[j]); }
      *(u16x8*)&dst[(size_t)fi * 8] = *(u16x8*)us;
    }
  } else if (bx < 336) {
    int i = (bx - 144) * 256 + tid;               // 0..49151
    Wbv[i] = isbf ? ((const u16*)wv)[i] : f2b(((const float*)wv)[i]);
  } else {
    int i = (bx - 336) * 256 + tid;               // 0..39935
    if (i < 39936) {
      int gc = i / 104, t = i - gc * 104;
      float lo = 0.f, hi = 0.f;
      if (t < 56) {
        int al = (t >= 28) ? 1 : 0;
        int u = t - al * 28;
        int dy = u >> 2, p = u & 3;
        size_t base = (size_t)gc * 49 + dy * 7;
        if (!al) {
          lo = ldf(wdw7, base + 2 * p, isbf);
          hi = (2 * p + 1 < 7) ? ldf(wdw7, base + 2 * p + 1, isbf) : 0.f;
        } else {
          lo = (p == 0) ? 0.f : ldf(wdw7, base + 2 * p - 1, isbf);
          hi = ldf(wdw7, base + 2 * p, isbf);
        }
      } else if (t < 86) {
        int al = (t >= 71) ? 1 : 0;
        int u = t - (al ? 71 : 56);
        int dy = u / 3, p = u % 3;
        size_t base = (size_t)gc * 25 + dy * 5;
        if (!al) {
          lo = ldf(wdw5, base + 2 * p, isbf);
          hi = (2 * p + 1 < 5) ? ldf(wdw5, base + 2 * p + 1, isbf) : 0.f;
        } else {
          lo = (p == 0) ? 0.f : ldf(wdw5, base + 2 * p - 1, isbf);
          hi = ldf(wdw5, base + 2 * p, isbf);
        }
      } else if (t < 98) {
        int al = (t >= 92) ? 1 : 0;
        int u = t - (al ? 92 : 86);
        int dy = u >> 1, p = u & 1;
        size_t base = (size_t)gc * 9 + dy * 3;
        if (!al) {
          lo = ldf(wdw3, base + 2 * p, isbf);
          hi = (2 * p + 1 < 3) ? ldf(wdw3, base + 2 * p + 1, isbf) : 0.f;
        } else {
          lo = (p == 0) ? 0.f : ldf(wdw3, base + 2 * p - 1, isbf);
          hi = ldf(wdw3, base + 2 * p, isbf);
        }
      }
      Wdwp[i] = (unsigned)f2h(lo) | ((unsigned)f2h(hi) << 16);
    }
  }
}

// ---------------------------------------------------------------------------
// MFMA GEMM v6: C[b][o][n] = sum_c A[o][c] * X[b][c][n], K=128, M=384.
// A fragment-ordered; LDS-transpose epilogue (16B stores). xq written FP16
// (tighter than bf16 for |x|<=65k) to enable fdot2 conv downstream.
// ---------------------------------------------------------------------------
__global__ __launch_bounds__(256) void gemm_mfma(
    const u16* __restrict__ Wb,
    const void* __restrict__ X,
    u16* __restrict__ C, long c_bstride, int M,
    const int* __restrict__ flagp)
{
  const int isbf = *flagp;
  __shared__ u16 Xs[128 * 76];    // 19456 B
  __shared__ u16 Cs[128 * 72];    // 18432 B
  const int b = blockIdx.z;
  const int n0 = blockIdx.x * 64;
  const int tid = threadIdx.x;
  const size_t xbase = (size_t)b * 2097152 + n0;  // 128*NSP per batch

  if (isbf) {
    const u16* Xp = (const u16*)X;
#pragma unroll
    for (int i = 0; i < 4; i++) {
      int s = i * 256 + tid;
      int kk = s >> 3, p = (s & 7) * 8;
      u32x4 v = *(const u32x4*)(Xp + xbase + (size_t)kk * NSP + p);
      uint2 lo; lo.x = v[0]; lo.y = v[1];
      uint2 hi; hi.x = v[2]; hi.y = v[3];
      *(uint2*)&Xs[kk * 76 + p]     = lo;
      *(uint2*)&Xs[kk * 76 + p + 4] = hi;
    }
  } else {
    const float* Xp = (const float*)X;
#pragma unroll
    for (int i = 0; i < 4; i++) {
      int s = i * 256 + tid;
      int kk = s >> 3, p = (s & 7) * 8;
      f32x4 fa = *(const f32x4*)(Xp + xbase + (size_t)kk * NSP + p);
      f32x4 fb = *(const f32x4*)(Xp + xbase + (size_t)kk * NSP + p + 4);
      u16 u8v[8];
#pragma unroll
      for (int j = 0; j < 4; j++) u8v[j] = f2b(fa[j]);
#pragma unroll
      for (int j = 0; j < 4; j++) u8v[4 + j] = f2b(fb[j]);
      *(uint2*)&Xs[kk * 76 + p]     = *(uint2*)&u8v[0];
      *(uint2*)&Xs[kk * 76 + p + 4] = *(uint2*)&u8v[4];
    }
  }
  __syncthreads();

  const int wid = tid >> 6, lane = tid & 63;
  const int quad = lane >> 4, col = lane & 15;
  const int nw = wid * 16;
  u16* Cb = C + (size_t)b * c_bstride + n0;
  const short8_* Af = (const short8_*)Wb;

  for (int ob = 0; ob < M; ob += 128) {
    const int obi = ob >> 7;
    f32x4 z = {0.f, 0.f, 0.f, 0.f};
    f32x4 acc[8];
#pragma unroll
    for (int m = 0; m < 8; m++) acc[m] = z;

#pragma unroll
    for (int ks = 0; ks < 4; ks++) {
      const int k0 = ks * 32;
      short8_ bfrag;
#pragma unroll
      for (int j = 0; j < 8; j++)
        bfrag[j] = (short)Xs[(k0 + quad * 8 + j) * 76 + nw + col];
#pragma unroll
      for (int m = 0; m < 8; m++) {
        short8_ afrag = Af[(size_t)(((obi * 4 + ks) * 8 + m) * 64 + lane)];
        acc[m] = __builtin_amdgcn_mfma_f32_16x16x32_bf16(afrag, bfrag, acc[m], 0, 0, 0);
      }
    }

    // epilogue: acc -> Cs (FP16 values), then coalesced 16B global stores
    if (ob) __syncthreads();
#pragma unroll
    for (int m = 0; m < 8; m++)
#pragma unroll
      for (int r = 0; r < 4; r++)
        Cs[(m * 16 + quad * 4 + r) * 72 + nw + col] = f2h(acc[m][r]);
    __syncthreads();
#pragma unroll
    for (int i = 0; i < 4; i++) {
      int u = i * 256 + tid;
      int row = u >> 3, off = (u & 7) * 8;
      u16x8 v = *(const u16x8*)&Cs[row * 72 + off];
      *(u16x8*)(Cb + (size_t)(ob + row) * NSP + off) = v;
    }
  }
}

// ---------------------------------------------------------------------------
// convgemm v9: conv via v_dot2_f32_f16 (2 MACs/instr, zero unpack).
// xq is FP16; LDS row words ARE fp16 pairs; weight pair tables (A/B
// alignments) staged from Wdwp. 392 fdot2/chunk vs 664 FMA + 98 unpack.
// Keeps: aliased Bp, hreg prefetch, hoisted geometry, XCD swizzle.
// ---------------------------------------------------------------------------
__global__ __launch_bounds__(256) void convgemm(
    const u16* __restrict__ xqg, long x_bstride, long x_gstride, int gc_base0,
    const unsigned* __restrict__ Wdwp,
    const u16* __restrict__ Afrag, long a_bstride, long a_gstride,
    void* __restrict__ Out, long out_gstride, int om,
    const int* __restrict__ flagp)
{
  const int isbf = *flagp;
  __shared__ u16 regA[7680];     // in_s (32ch x 240) UNION Bp (96 x 68)
  __shared__ unsigned dwp[3328]; // 32ch x 104 pair-words : 13312 B
  u16* in_s = regA;
  u16* Bp = regA;
  const int b = blockIdx.z, g = blockIdx.y;
  const int t0 = blockIdx.x;
  const int t = ((t0 & 7) << 5) | (t0 >> 3);   // XCD swizzle
  const int y0 = (t >> 3) * 4, x0 = (t & 7) * 16;
  const u16* xb = xqg + (size_t)b * x_bstride + (size_t)g * x_gstride;
  const short8_* Af = (const short8_*)(Afrag + (size_t)b * a_bstride + (size_t)g * a_gstride);
  const int gc_base = gc_base0 + g * 128;
  const int tid = threadIdx.x;
  const int cc_t = tid >> 3;
  const int py_t = (tid >> 1) & 3;
  const int xh   = tid & 1;
  const int wid = tid >> 6, lane = tid & 63;
  const int quad = lane >> 4, col = lane & 15;

  // hoisted staging geometry
  const int hy  = lane / 6;
  const int hc4 = lane - hy * 6;
  const int gy_s = y0 - 3 + hy, gx_s = x0 - 4 + hc4 * 4;
  const bool sval = (lane < 60);
  const bool gok = sval && ((unsigned)gy_s < 128u) && ((unsigned)gx_s <= 124u);
  const u16* gsrc0 = xb + (size_t)wid * NSP + (gy_s * 128 + gx_s);
  const int ldso = wid * 240 + hy * 24 + hc4 * 4;

  uint2 hreg[8];
#pragma unroll
  for (int i = 0; i < 8; i++) {
    uint2 v; v.x = 0u; v.y = 0u;
    if (gok) v = *(const uint2*)(gsrc0 + (size_t)(i * 4) * NSP);
    hreg[i] = v;
  }

  f32x4 z = {0.f, 0.f, 0.f, 0.f};
  f32x4 acc[8];
#pragma unroll
  for (int m = 0; m < 8; m++) acc[m] = z;

  for (int chn = 0; chn < 4; chn++) {
    const int c0 = chn * 32;
    if (chn) __syncthreads();   // B4

    if (sval) {
#pragma unroll
      for (int i = 0; i < 8; i++)
        *(uint2*)&in_s[ldso + i * 960] = hreg[i];
    }
    {
      const u32x4* wg = (const u32x4*)(Wdwp + (size_t)(gc_base + c0) * 104);
#pragma unroll
      for (int i = 0; i < 4; i++) {
        int s = i * 256 + tid;
        if (s < 832) ((u32x4*)dwp)[s] = wg[s];
      }
    }
    __syncthreads();            // B1

    if (chn < 3) {
      const u16* gsrc = gsrc0 + (size_t)(c0 + 32) * NSP;
#pragma unroll
      for (int i = 0; i < 8; i++) {
        uint2 v; v.x = 0u; v.y = 0u;
        if (gok) v = *(const uint2*)(gsrc + (size_t)(i * 4) * NSP);
        hreg[i] = v;
      }
    }

    // --- conv via fdot2: 3 scales, 8 px per thread ---
    float a0[8], a1[8], a2[8];
#pragma unroll
    for (int px = 0; px < 8; px++) { a0[px] = 0.f; a1[px] = 0.f; a2[px] = 0.f; }
    {
      const unsigned* wch = dwp + cc_t * 104;
      const u16* rowbase = in_s + cc_t * 240 + xh * 8;
#pragma unroll
      for (int dy = 0; dy < 7; dy++) {
        const u16* rp = rowbase + (py_t + dy) * 24;
        u32x4 ra = *(const u32x4*)rp;
        u32x4 rb = *(const u32x4*)(rp + 8);
        unsigned W[8];
#pragma unroll
        for (int j = 0; j < 4; j++) { W[j] = ra[j]; W[4 + j] = rb[j]; }
        {
          const unsigned* A2w = wch + dy * 4;
          const unsigned* B2w = wch + 28 + dy * 4;
#pragma unroll
          for (int e = 0; e < 4; e++) {
            float s = a2[2 * e];
            s = fdot2u(W[e],     B2w[0], s);
            s = fdot2u(W[e + 1], B2w[1], s);
            s = fdot2u(W[e + 2], B2w[2], s);
            s = fdot2u(W[e + 3], B2w[3], s);
            a2[2 * e] = s;
            float u = a2[2 * e + 1];
            u = fdot2u(W[e + 1], A2w[0], u);
            u = fdot2u(W[e + 2], A2w[1], u);
            u = fdot2u(W[e + 3], A2w[2], u);
            u = fdot2u(W[e + 4], A2w[3], u);
            a2[2 * e + 1] = u;
          }
        }
        if (dy >= 1 && dy <= 5) {
          const unsigned* A1w = wch + 56 + (dy - 1) * 3;
          const unsigned* B1w = wch + 71 + (dy - 1) * 3;
#pragma unroll
          for (int e = 0; e < 4; e++) {
            float s = a1[2 * e];
            s = fdot2u(W[e + 1], A1w[0], s);
            s = fdot2u(W[e + 2], A1w[1], s);
            s = fdot2u(W[e + 3], A1w[2], s);
            a1[2 * e] = s;
            float u = a1[2 * e + 1];
            u = fdot2u(W[e + 1], B1w[0], u);
            u = fdot2u(W[e + 2], B1w[1], u);
            u = fdot2u(W[e + 3], B1w[2], u);
            a1[2 * e + 1] = u;
          }
        }
        if (dy >= 2 && dy <= 4) {
          const unsigned* A0w = wch + 86 + (dy - 2) * 2;
          const unsigned* B0w = wch + 92 + (dy - 2) * 2;
#pragma unroll
          for (int e = 0; e < 4; e++) {
            float s = a0[2 * e];
            s = fdot2u(W[e + 1], B0w[0], s);
            s = fdot2u(W[e + 2], B0w[1], s);
            a0[2 * e] = s;
            float u = a0[2 * e + 1];
            u = fdot2u(W[e + 2], A0w[0], u);
            u = fdot2u(W[e + 3], A0w[1], u);
            a0[2 * e + 1] = u;
          }
        }
      }
    }
    __syncthreads();            // B2: in_s reads done -> regA reusable

    // write Bp (over in_s region), bf16 as before
    {
      const int pb = py_t * 16 + xh * 8;
      u16 us[8];
#pragma unroll
      for (int px = 0; px < 8; px++) us[px] = f2b(a0[px]);
      *(uint2*)&Bp[(0 * 32 + cc_t) * 68 + pb]     = *(uint2*)&us[0];
      *(uint2*)&Bp[(0 * 32 + cc_t) * 68 + pb + 4] = *(uint2*)&us[4];
#pragma unroll
      for (int px = 0; px < 8; px++) us[px] = f2b(a1[px]);
      *(uint2*)&Bp[(1 * 32 + cc_t) * 68 + pb]     = *(uint2*)&us[0];
      *(uint2*)&Bp[(1 * 32 + cc_t) * 68 + pb + 4] = *(uint2*)&us[4];
#pragma unroll
      for (int px = 0; px < 8; px++) us[px] = f2b(a2[px]);
      *(uint2*)&Bp[(2 * 32 + cc_t) * 68 + pb]     = *(uint2*)&us[0];
      *(uint2*)&Bp[(2 * 32 + cc_t) * 68 + pb + 4] = *(uint2*)&us[4];
    }
    __syncthreads();            // B3: Bp ready

    // MFMA accumulate
#pragma unroll
    for (int s = 0; s < 3; s++) {
      const int k0 = s * 32;
      short8_ bfrag;
#pragma unroll
      for (int j = 0; j < 8; j++)
        bfrag[j] = (short)Bp[(k0 + quad * 8 + j) * 68 + wid * 16 + col];
#pragma unroll
      for (int m = 0; m < 8; m++) {
        short8_ afrag = Af[(size_t)(((s * 4 + chn) * 8 + m) * 64 + lane)];
        acc[m] = __builtin_amdgcn_mfma_f32_16x16x32_bf16(afrag, bfrag, acc[m], 0, 0, 0);
      }
    }
  }

  // epilogue
#pragma unroll
  for (int m = 0; m < 8; m++)
#pragma unroll
    for (int r = 0; r < 4; r++) {
      int o = m * 16 + quad * 4 + r;
      int ng = (y0 + wid) * 128 + x0 + col;
      size_t base = ((size_t)b * 128 + o) * NSP + ng;
      if (om && !isbf) ((float*)Out)[base] = acc[m][r];
      else ((u16*)Out + (size_t)g * out_gstride)[base] = f2b(acc[m][r]);
    }
}

// ---------------------------------------------------------------------------
// s_mfma: S[b][h] (16x16) = q_h · k_h^T via MFMA + fused qs/ks norms.
// ---------------------------------------------------------------------------
__global__ __launch_bounds__(256) void s_mfma(
    const u16* __restrict__ qb, const u16* __restrict__ kb,
    float* __restrict__ S, float* __restrict__ qs, float* __restrict__ ks)
{
  __shared__ u16 Qs[16 * 520];   // 16640 B
  __shared__ u16 Ks[16 * 520];   // 16640 B
  const int chunk = blockIdx.x, h = blockIdx.y, b = blockIdx.z;
  const int tid = threadIdx.x;
  const int n0 = chunk * 512;
  const size_t gbase = ((size_t)b * 128 + h * 16) * NSP + n0;

#pragma unroll
  for (int i = 0; i < 4; i++) {
    int idx = i * 256 + tid;            // 0..1023
    int row = idx >> 6, off = (idx & 63) * 8;
    *(u16x8*)&Qs[row * 520 + off] = *(const u16x8*)(qb + gbase + (size_t)row * NSP + off);
    *(u16x8*)&Ks[row * 520 + off] = *(const u16x8*)(kb + gbase + (size_t)row * NSP + off);
  }
  __syncthreads();

  const int wid = tid >> 6, lane = tid & 63;
  const int quad = lane >> 4, col = lane & 15;
  const int nb = wid * 128;
  f32x4 acc = {0.f, 0.f, 0.f, 0.f};
  float sq = 0.f, sk = 0.f;
#pragma unroll
  for (int k2 = 0; k2 < 4; k2++) {
    int off = nb + k2 * 32 + quad * 8;
    short8_ qf = *(const short8_*)&Qs[col * 520 + off];
    short8_ kf = *(const short8_*)&Ks[col * 520 + off];
#pragma unroll
    for (int j = 0; j < 8; j++) {
      float qv = b2f((u16)qf[j]), kv = b2f((u16)kf[j]);
      sq += qv * qv; sk += kv * kv;
    }
    acc = __builtin_amdgcn_mfma_f32_16x16x32_bf16(qf, kf, acc, 0, 0, 0);
  }

  sq += __shfl_xor(sq, 16); sq += __shfl_xor(sq, 32);
  sk += __shfl_xor(sk, 16); sk += __shfl_xor(sk, 32);
  if (quad == 0) {
    atomicAdd(&qs[b * 128 + h * 16 + col], sq);
    atomicAdd(&ks[b * 128 + h * 16 + col], sk);
  }

  __syncthreads();
  float* Sred = (float*)Qs;
#pragma unroll
  for (int r = 0; r < 4; r++)
    Sred[wid * 256 + (quad * 4 + r) * 16 + col] = acc[r];
  __syncthreads();
  {
    float v = Sred[tid] + Sred[256 + tid] + Sred[512 + tid] + Sred[768 + tid];
    atomicAdd(&S[((size_t)(b * 8 + h) << 8) + tid], v);
  }
}

// ---------------------------------------------------------------------------
// fold Wmv[b] = Mmat[b] (128x128) @ Wbv (128x384); output FRAGMENT-ORDERED.
// ---------------------------------------------------------------------------
__global__ __launch_bounds__(256) void fold_wv(
    const u16* __restrict__ Mmat, const u16* __restrict__ Wbv,
    u16* __restrict__ Wmv)
{
  const int b = blockIdx.y, jb = blockIdx.x;   // grid (12, 8)
  const u16* Mb = Mmat + (size_t)b * 16384;
  const int t = threadIdx.x;
  const int o = t >> 1, jh = t & 1;
  const int j0 = jb * 32 + jh * 16;
  float acc[16];
#pragma unroll
  for (int jj = 0; jj < 16; jj++) acc[jj] = 0.f;
  for (int d = 0; d < 128; d++) {
    float mv = b2f(Mb[o * 128 + d]);
    const u16* wr = Wbv + (size_t)d * 384 + j0;
#pragma unroll
    for (int jj = 0; jj < 16; jj++) acc[jj] += mv * b2f(wr[jj]);
  }
  const int kc = j0 >> 7, ks = (j0 >> 5) & 3, q0 = (j0 >> 3) & 3;
  const int m = o >> 4, col = o & 15;
  u16* outb = Wmv + (size_t)b * 49152;
  const int fi0 = ((kc * 4 + ks) * 8 + m) * 64 + q0 * 16 + col;
  u16x8 v8;
#pragma unroll
  for (int jj = 0; jj < 8; jj++) v8[jj] = f2b(acc[jj]);
  *(u16x8*)&outb[(size_t)fi0 * 8] = v8;
#pragma unroll
  for (int jj = 0; jj < 8; jj++) v8[jj] = f2b(acc[8 + jj]);
  *(u16x8*)&outb[(size_t)(fi0 + 16) * 8] = v8;
}

// ---------------------------------------------------------------------------
// attn = softmax_d( S / (max(|q|,eps)max(|k|,eps)) * T[h] );
// M_b[o][h*16+e] = sum_d w_out[o][h*16+d] attn[h][d][e]
// ---------------------------------------------------------------------------
__global__ __launch_bounds__(256) void attn_mat(
    const float* __restrict__ S, const float* __restrict__ qs,
    const float* __restrict__ ks,
    const void* __restrict__ w_out, const void* __restrict__ temp,
    u16* __restrict__ Mmat, const int* __restrict__ flagp)
{
  const int isbf = *flagp;
  const int b = blockIdx.x;
  __shared__ float attn_s[8 * 16 * 16];
  const int t = threadIdx.x;
  if (t < 128) {
    int h = t >> 4, c = t & 15;
    float qn = fmaxf(sqrtf(fmaxf(qs[b * 128 + h * 16 + c], 0.f)), 1e-12f);
    float tm = ldf(temp, h, isbf);
    float zv[16];
    float m = -1e30f;
    for (int d = 0; d < 16; d++) {
      float kn = fmaxf(sqrtf(fmaxf(ks[b * 128 + h * 16 + d], 0.f)), 1e-12f);
      zv[d] = S[(((size_t)b * 8 + h) * 16 + c) * 16 + d] / (qn * kn) * tm;
      m = fmaxf(m, zv[d]);
    }
    float sum = 0.f;
    for (int d = 0; d < 16; d++) { zv[d] = expf(zv[d] - m); sum += zv[d]; }
    float inv = 1.f / sum;
    for (int d = 0; d < 16; d++) attn_s[(h * 16 + c) * 16 + d] = zv[d] * inv;
  }
  __syncthreads();
  for (int idx = t; idx < 128 * 128; idx += 256) {
    int o = idx >> 7, cp = idx & 127;
    int h = cp >> 4, e = cp & 15;
    float a = 0.f;
    for (int d = 0; d < 16; d++)
      a += ldf(w_out, (size_t)o * 128 + h * 16 + d, isbf) * attn_s[(h * 16 + d) * 16 + e];
    Mmat[(size_t)b * 16384 + idx] = f2b(a);
  }
}

// ---------------------------------------------------------------------------
// Workspace layout (~169.3 MB; >=236 MB proven):
//   xq @ 0: UNIFIED [b][384][NSP] FP16 = 100.7 MB
//   q  @ 100663296 | k @ 134217728
//   tail @ 167772160: S(64K) qs(4K) ks(4K) flag(128B) Mmat(256K) Wbv(96K)
//                     Wmv(768K) Wdwp(156K u32 pair table)
// d_out scratch (u16): Wbqf@0 Wbkf@49152 Wbkvf@98304.
// ---------------------------------------------------------------------------
extern "C" void kernel_launch(void* const* d_in, const int* in_sizes, int n_in,
                              void* d_out, int out_size, void* d_ws, size_t ws_size,
                              hipStream_t stream) {
  const void* x     = d_in[0];
  const void* w_qkv = d_in[1];
  const void* w_dw3 = d_in[2];
  const void* w_dw5 = d_in[3];
  const void* w_dw7 = d_in[4];
  const void* w_q   = d_in[5];
  const void* w_k   = d_in[6];
  const void* w_v   = d_in[7];
  const void* w_o   = d_in[8];
  const void* temp  = d_in[9];

  char* ws = (char*)d_ws;
  u16* dsc = (u16*)d_out;
  u16* Wbqf  = dsc;
  u16* Wbkf  = dsc + 49152;
  u16* Wbkvf = dsc + 98304;

  u16* xq    = (u16*)ws;                     // [b][384][NSP] fp16
  u16* q     = (u16*)(ws + 100663296);
  char* tail = ws + 167772160;
  float* S   = (float*)tail;
  float* qs  = (float*)(tail + 65536);
  float* ks  = (float*)(tail + 69632);
  int* flag  = (int*)(tail + 73728);
  u16* Mmat  = (u16*)(tail + 73856);
  u16* Wbv   = (u16*)(tail + 336000);
  u16* Wmv   = (u16*)(tail + 434304);
  unsigned* Wdwp = (unsigned*)(tail + 1220736);   // 39936 u32 = 156 KB
  u16* k     = q + 16777216;

  // all preps + init in one launch
  prep_all<<<492, 256, 0, stream>>>(
      w_q, w_k, w_qkv, w_v, w_dw3, w_dw5, w_dw7, temp,
      Wbqf, Wbkf, Wbkvf, Wbv, Wdwp, flag, S);

  // xq (ALL 384 rows of w_qkv) in one dispatch, fp16 out
  gemm_mfma<<<dim3(256, 1, NB), 256, 0, stream>>>(
      Wbkvf, x, xq, 384L * NSP, 384, flag);

  // q + k fused conv+proj in ONE launch (gridDim.y = 2)
  convgemm<<<dim3(256, 2, NB), 256, 0, stream>>>(
      xq, 384L * NSP, 128L * NSP, 0, Wdwp,
      Wbqf, 0, 49152, q, 16777216L, 0, flag);

  // S/qs/ks via MFMA
  s_mfma<<<dim3(32, 8, NB), 256, 0, stream>>>(q, k, S, qs, ks);

  attn_mat<<<NB, 256, 0, stream>>>(S, qs, ks, w_o, temp, Mmat, flag);
  fold_wv<<<dim3(12, NB), 256, 0, stream>>>(Mmat, Wbv, Wmv);

  // v: fused conv + (M_b@Wv) -> out (reads group 2 of unified xq)
  convgemm<<<dim3(256, 1, NB), 256, 0, stream>>>(
      xq + 256L * NSP, 384L * NSP, 0, 256, Wdwp,
      Wmv, 49152, 0, d_out, 0, 1, flag);
}

// Round 18
// 479.511 us; speedup vs baseline: 1.1004x; 1.1004x over previous
//
#include <hip/hip_runtime.h>
#include <hip/hip_bf16.h>

// Problem constants
#define NB 8
#define NSP 16384      // 128*128

typedef unsigned short u16;
typedef __attribute__((ext_vector_type(8))) short short8_;
typedef __attribute__((ext_vector_type(8))) unsigned short u16x8;
typedef __attribute__((ext_vector_type(4))) float f32x4;
typedef __attribute__((ext_vector_type(4))) unsigned u32x4;

__device__ __forceinline__ float b2f(u16 u) {
  unsigned v = ((unsigned)u) << 16;
  float f;
  __builtin_memcpy(&f, &v, 4);
  return f;
}
__device__ __forceinline__ u16 f2b(float f) {
  __hip_bfloat16 h = __float2bfloat16(f);  // RNE
  u16 u;
  __builtin_memcpy(&u, &h, 2);
  return u;
}
__device__ __forceinline__ float ldf(const void* p, size_t i, int isbf) {
  return isbf ? b2f(((const u16*)p)[i]) : ((const float*)p)[i];
}

// ---------------------------------------------------------------------------
// prep_all: ONE launch replacing all preps (dtype probed per-thread).
// Blocks:   0- 71: zero S/qs/ks (18432 f32) + write flag
//          72-143: fragment-order w_q/w_k/w_qkv (3 mats x 24 blocks)
//         144-335: bf16 copy w_v (49152)
//         336-461: pack dw weights Wdww[384][84] f32
// ---------------------------------------------------------------------------
__global__ __launch_bounds__(256) void prep_all(
    const void* __restrict__ wq, const void* __restrict__ wk,
    const void* __restrict__ wqkv, const void* __restrict__ wv,
    const void* __restrict__ wdw3, const void* __restrict__ wdw5,
    const void* __restrict__ wdw7, const void* __restrict__ temp,
    u16* __restrict__ Wqf, u16* __restrict__ Wkf, u16* __restrict__ Wkvf,
    u16* __restrict__ Wbv, float* __restrict__ Wdww,
    int* __restrict__ flag, float* __restrict__ Sz)
{
  const int isbf = (((const u16*)temp)[0] != 0) ? 1 : 0;
  const int bx = blockIdx.x;
  const int tid = threadIdx.x;

  if (bx < 72) {
    int i = bx * 256 + tid;
    if (i == 0) *flag = isbf;
    if (i < 18432) Sz[i] = 0.f;
  } else if (bx < 144) {
    const int mb = bx - 72;
    const int mat = mb / 24;
    const int fi = (mb - mat * 24) * 256 + tid;   // 0..6143
    const int lane = fi & 63, m = (fi >> 6) & 7, ks = (fi >> 9) & 3, blk = fi >> 11;
    const int quad = lane >> 4, col = lane & 15;
    const void* src;
    u16* dst;
    size_t so;
    if (mat == 2) {
      so = (size_t)(blk * 128 + m * 16 + col) * 128 + ks * 32 + quad * 8;
      src = wqkv; dst = Wkvf;
    } else {
      so = (size_t)(m * 16 + col) * 384 + blk * 128 + ks * 32 + quad * 8;
      src = mat ? wk : wq; dst = mat ? Wkf : Wqf;
    }
    if (isbf) {
      *(u16x8*)&dst[(size_t)fi * 8] = *(const u16x8*)((const u16*)src + so);
    } else {
      f32x4 a = *(const f32x4*)((const float*)src + so);
      f32x4 b = *(const f32x4*)((const float*)src + so + 4);
      u16 us[8];
#pragma unroll
      for (int j = 0; j < 4; j++) { us[j] = f2b(a[j]); us[4 + j] = f2b(b[j]); }
      *(u16x8*)&dst[(size_t)fi * 8] = *(u16x8*)us;
    }
  } else if (bx < 336) {
    int i = (bx - 144) * 256 + tid;               // 0..49151
    Wbv[i] = isbf ? ((const u16*)wv)[i] : f2b(((const float*)wv)[i]);
  } else {
    int i = (bx - 336) * 256 + tid;               // 0..32255
    if (i >= 32256) return;
    int gc = i / 84, t = i - gc * 84;
    float v = 0.f;
    if (t < 9)       v = ldf(wdw3, (size_t)gc * 9 + t, isbf);
    else if (t < 34) v = ldf(wdw5, (size_t)gc * 25 + (t - 9), isbf);
    else if (t < 83) v = ldf(wdw7, (size_t)gc * 49 + (t - 34), isbf);
    Wdww[i] = v;
  }
}

// ---------------------------------------------------------------------------
// MFMA GEMM v5: C[b][o][n] = sum_c A[o][c] * X[b][c][n], K=128, M=384 in one
// dispatch. A fragment-ordered. LDS-transpose epilogue — C-tile staged in
// Cs[128][72] then streamed out as 128B-contiguous dwordx4 stores.
// ---------------------------------------------------------------------------
__global__ __launch_bounds__(256) void gemm_mfma(
    const u16* __restrict__ Wb,
    const void* __restrict__ X,
    u16* __restrict__ C, long c_bstride, int M,
    const int* __restrict__ flagp)
{
  const int isbf = *flagp;
  __shared__ u16 Xs[128 * 76];    // 19456 B
  __shared__ u16 Cs[128 * 72];    // 18432 B (rows 144B: 16B-aligned)
  const int b = blockIdx.z;
  const int n0 = blockIdx.x * 64;
  const int tid = threadIdx.x;
  const size_t xbase = (size_t)b * 2097152 + n0;  // 128*NSP per batch

  if (isbf) {
    const u16* Xp = (const u16*)X;
#pragma unroll
    for (int i = 0; i < 4; i++) {
      int s = i * 256 + tid;
      int kk = s >> 3, p = (s & 7) * 8;
      u32x4 v = *(const u32x4*)(Xp + xbase + (size_t)kk * NSP + p);
      uint2 lo; lo.x = v[0]; lo.y = v[1];
      uint2 hi; hi.x = v[2]; hi.y = v[3];
      *(uint2*)&Xs[kk * 76 + p]     = lo;
      *(uint2*)&Xs[kk * 76 + p + 4] = hi;
    }
  } else {
    const float* Xp = (const float*)X;
#pragma unroll
    for (int i = 0; i < 4; i++) {
      int s = i * 256 + tid;
      int kk = s >> 3, p = (s & 7) * 8;
      f32x4 fa = *(const f32x4*)(Xp + xbase + (size_t)kk * NSP + p);
      f32x4 fb = *(const f32x4*)(Xp + xbase + (size_t)kk * NSP + p + 4);
      u16 u8v[8];
#pragma unroll
      for (int j = 0; j < 4; j++) u8v[j] = f2b(fa[j]);
#pragma unroll
      for (int j = 0; j < 4; j++) u8v[4 + j] = f2b(fb[j]);
      *(uint2*)&Xs[kk * 76 + p]     = *(uint2*)&u8v[0];
      *(uint2*)&Xs[kk * 76 + p + 4] = *(uint2*)&u8v[4];
    }
  }
  __syncthreads();

  const int wid = tid >> 6, lane = tid & 63;
  const int quad = lane >> 4, col = lane & 15;
  const int nw = wid * 16;
  u16* Cb = C + (size_t)b * c_bstride + n0;
  const short8_* Af = (const short8_*)Wb;

  for (int ob = 0; ob < M; ob += 128) {
    const int obi = ob >> 7;
    f32x4 z = {0.f, 0.f, 0.f, 0.f};
    f32x4 acc[8];
#pragma unroll
    for (int m = 0; m < 8; m++) acc[m] = z;

#pragma unroll
    for (int ks = 0; ks < 4; ks++) {
      const int k0 = ks * 32;
      short8_ bfrag;
#pragma unroll
      for (int j = 0; j < 8; j++)
        bfrag[j] = (short)Xs[(k0 + quad * 8 + j) * 76 + nw + col];
#pragma unroll
      for (int m = 0; m < 8; m++) {
        short8_ afrag = Af[(size_t)(((obi * 4 + ks) * 8 + m) * 64 + lane)];
        acc[m] = __builtin_amdgcn_mfma_f32_16x16x32_bf16(afrag, bfrag, acc[m], 0, 0, 0);
      }
    }

    // epilogue: acc -> Cs (MFMA layout), then coalesced 16B global stores
    if (ob) __syncthreads();           // prev ob's Cs reads done
#pragma unroll
    for (int m = 0; m < 8; m++)
#pragma unroll
      for (int r = 0; r < 4; r++)
        Cs[(m * 16 + quad * 4 + r) * 72 + nw + col] = f2b(acc[m][r]);
    __syncthreads();                   // Cs ready
#pragma unroll
    for (int i = 0; i < 4; i++) {
      int u = i * 256 + tid;           // 0..1023: row=u>>3, off=(u&7)*8
      int row = u >> 3, off = (u & 7) * 8;
      u16x8 v = *(const u16x8*)&Cs[row * 72 + off];
      *(u16x8*)(Cb + (size_t)(ob + row) * NSP + off) = v;
    }
  }
}

// ---------------------------------------------------------------------------
// convgemm v8 (r14-proven, best): aliased Bp, un-split conv, hreg prefetch,
// hoisted staging geometry, XCD-aware tile swizzle (FETCH 172->45MB).
// FROZEN — structural 3-wave plateau characterized r7-r13; r17 proved
// VALU-reduction (fdot2) hurts: conv instructions hide LDS latency.
// ---------------------------------------------------------------------------
__global__ __launch_bounds__(256) void convgemm(
    const u16* __restrict__ xqg, long x_bstride, long x_gstride, int gc_base0,
    const float* __restrict__ Wdww,
    const u16* __restrict__ Afrag, long a_bstride, long a_gstride,
    void* __restrict__ Out, long out_gstride, int om,
    const int* __restrict__ flagp)
{
  const int isbf = *flagp;
  __shared__ u16 regA[7680];     // in_s (32ch x 240) UNION Bp (96 x 68)
  __shared__ float dww[2688];    // 32ch x 84
  u16* in_s = regA;
  u16* Bp = regA;
  const int b = blockIdx.z, g = blockIdx.y;
  const int t0 = blockIdx.x;
  const int t = ((t0 & 7) << 5) | (t0 >> 3);   // XCD swizzle: 8 bands of 32 tiles
  const int y0 = (t >> 3) * 4, x0 = (t & 7) * 16;
  const u16* xb = xqg + (size_t)b * x_bstride + (size_t)g * x_gstride;
  const short8_* Af = (const short8_*)(Afrag + (size_t)b * a_bstride + (size_t)g * a_gstride);
  const int gc_base = gc_base0 + g * 128;
  const int tid = threadIdx.x;
  const int cc_t = tid >> 3;
  const int py_t = (tid >> 1) & 3;
  const int xh   = tid & 1;
  const int wid = tid >> 6, lane = tid & 63;
  const int quad = lane >> 4, col = lane & 15;

  // ---- hoisted staging geometry (invariant across chunks and i) ----
  const int hy  = lane / 6;
  const int hc4 = lane - hy * 6;
  const int gy_s = y0 - 3 + hy, gx_s = x0 - 4 + hc4 * 4;
  const bool sval = (lane < 60);
  const bool gok = sval && ((unsigned)gy_s < 128u) && ((unsigned)gx_s <= 124u);
  const u16* gsrc0 = xb + (size_t)wid * NSP + (gy_s * 128 + gx_s);  // +(c0+i*4)*NSP
  const int ldso = wid * 240 + hy * 24 + hc4 * 4;                   // +i*960

  uint2 hreg[8];

  // prologue: chunk 0 halo -> regs
#pragma unroll
  for (int i = 0; i < 8; i++) {
    uint2 v; v.x = 0u; v.y = 0u;
    if (gok) v = *(const uint2*)(gsrc0 + (size_t)(i * 4) * NSP);
    hreg[i] = v;
  }

  f32x4 z = {0.f, 0.f, 0.f, 0.f};
  f32x4 acc[8];
#pragma unroll
  for (int m = 0; m < 8; m++) acc[m] = z;

  for (int chn = 0; chn < 4; chn++) {
    const int c0 = chn * 32;
    if (chn) __syncthreads();   // B4: prev MFMA done reading Bp (= regA)

    // halo regs -> LDS; weights global(L2-hot) -> LDS
    if (sval) {
#pragma unroll
      for (int i = 0; i < 8; i++)
        *(uint2*)&in_s[ldso + i * 960] = hreg[i];
    }
    {
      const float* wg = Wdww + (size_t)(gc_base + c0) * 84;
#pragma unroll
      for (int i = 0; i < 3; i++) {
        int s = i * 256 + tid;
        if (s < 672) *(f32x4*)&dww[s * 4] = *(const f32x4*)(wg + s * 4);
      }
    }
    __syncthreads();            // B1: in_s/dww ready

    // prefetch next chunk halo (hides under conv + MFMA below)
    if (chn < 3) {
      const u16* gsrc = gsrc0 + (size_t)(c0 + 32) * NSP;
#pragma unroll
      for (int i = 0; i < 8; i++) {
        uint2 v; v.x = 0u; v.y = 0u;
        if (gok) v = *(const uint2*)(gsrc + (size_t)(i * 4) * NSP);
        hreg[i] = v;
      }
    }

    // --- conv: 3 scales, 8 px per thread -> registers ---
    float a0[8], a1[8], a2[8];
#pragma unroll
    for (int px = 0; px < 8; px++) { a0[px] = 0.f; a1[px] = 0.f; a2[px] = 0.f; }
    {
      const float* dwc = dww + cc_t * 84;
      const u16* rowbase = in_s + cc_t * 240 + xh * 8;
#pragma unroll
      for (int dy = 0; dy < 7; dy++) {
        const u16* rp = rowbase + (py_t + dy) * 24;
        u32x4 ra = *(const u32x4*)rp;
        u32x4 rb = *(const u32x4*)(rp + 8);
        float row[14];
#pragma unroll
        for (int j = 0; j < 14; j++) {
          int l = j + 1;
          unsigned wd = (l < 8) ? ra[l >> 1] : rb[(l >> 1) - 4];
          unsigned bits = (l & 1) ? (wd & 0xffff0000u) : (wd << 16);
          __builtin_memcpy(&row[j], &bits, 4);
        }
#pragma unroll
        for (int dx = 0; dx < 7; dx++) {
          float wv = dwc[34 + dy * 7 + dx];
#pragma unroll
          for (int px = 0; px < 8; px++) a2[px] += row[px + dx] * wv;
        }
        if (dy >= 1 && dy <= 5) {
          int dy5 = dy - 1;
#pragma unroll
          for (int dx = 0; dx < 5; dx++) {
            float wv = dwc[9 + dy5 * 5 + dx];
#pragma unroll
            for (int px = 0; px < 8; px++) a1[px] += row[px + 1 + dx] * wv;
          }
        }
        if (dy >= 2 && dy <= 4) {
          int dy3 = dy - 2;
#pragma unroll
          for (int dx = 0; dx < 3; dx++) {
            float wv = dwc[dy3 * 3 + dx];
#pragma unroll
            for (int px = 0; px < 8; px++) a0[px] += row[px + 2 + dx] * wv;
          }
        }
      }
    }
    __syncthreads();            // B2: in_s reads done -> regA reusable

    // write Bp (over in_s region)
    {
      const int pb = py_t * 16 + xh * 8;
      u16 us[8];
#pragma unroll
      for (int px = 0; px < 8; px++) us[px] = f2b(a0[px]);
      *(uint2*)&Bp[(0 * 32 + cc_t) * 68 + pb]     = *(uint2*)&us[0];
      *(uint2*)&Bp[(0 * 32 + cc_t) * 68 + pb + 4] = *(uint2*)&us[4];
#pragma unroll
      for (int px = 0; px < 8; px++) us[px] = f2b(a1[px]);
      *(uint2*)&Bp[(1 * 32 + cc_t) * 68 + pb]     = *(uint2*)&us[0];
      *(uint2*)&Bp[(1 * 32 + cc_t) * 68 + pb + 4] = *(uint2*)&us[4];
#pragma unroll
      for (int px = 0; px < 8; px++) us[px] = f2b(a2[px]);
      *(uint2*)&Bp[(2 * 32 + cc_t) * 68 + pb]     = *(uint2*)&us[0];
      *(uint2*)&Bp[(2 * 32 + cc_t) * 68 + pb + 4] = *(uint2*)&us[4];
    }
    __syncthreads();            // B3: Bp ready

    // --- MFMA accumulate: K-slices (s=scale -> kc, chn -> ks) ---
#pragma unroll
    for (int s = 0; s < 3; s++) {
      const int k0 = s * 32;
      short8_ bfrag;
#pragma unroll
      for (int j = 0; j < 8; j++)
        bfrag[j] = (short)Bp[(k0 + quad * 8 + j) * 68 + wid * 16 + col];
#pragma unroll
      for (int m = 0; m < 8; m++) {
        short8_ afrag = Af[(size_t)(((s * 4 + chn) * 8 + m) * 64 + lane)];
        acc[m] = __builtin_amdgcn_mfma_f32_16x16x32_bf16(afrag, bfrag, acc[m], 0, 0, 0);
      }
    }
  }

  // epilogue
#pragma unroll
  for (int m = 0; m < 8; m++)
#pragma unroll
    for (int r = 0; r < 4; r++) {
      int o = m * 16 + quad * 4 + r;
      int ng = (y0 + wid) * 128 + x0 + col;
      size_t base = ((size_t)b * 128 + o) * NSP + ng;
      if (om && !isbf) ((float*)Out)[base] = acc[m][r];
      else ((u16*)Out + (size_t)g * out_gstride)[base] = f2b(acc[m][r]);
    }
}

// ---------------------------------------------------------------------------
// s_mfma: S[b][h] (16x16) = q_h · k_h^T via MFMA + fused qs/ks norms.
// ---------------------------------------------------------------------------
__global__ __launch_bounds__(256) void s_mfma(
    const u16* __restrict__ qb, const u16* __restrict__ kb,
    float* __restrict__ S, float* __restrict__ qs, float* __restrict__ ks)
{
  __shared__ u16 Qs[16 * 520];   // 16640 B
  __shared__ u16 Ks[16 * 520];   // 16640 B
  const int chunk = blockIdx.x, h = blockIdx.y, b = blockIdx.z;
  const int tid = threadIdx.x;
  const int n0 = chunk * 512;
  const size_t gbase = ((size_t)b * 128 + h * 16) * NSP + n0;

#pragma unroll
  for (int i = 0; i < 4; i++) {
    int idx = i * 256 + tid;            // 0..1023
    int row = idx >> 6, off = (idx & 63) * 8;
    *(u16x8*)&Qs[row * 520 + off] = *(const u16x8*)(qb + gbase + (size_t)row * NSP + off);
    *(u16x8*)&Ks[row * 520 + off] = *(const u16x8*)(kb + gbase + (size_t)row * NSP + off);
  }
  __syncthreads();

  const int wid = tid >> 6, lane = tid & 63;
  const int quad = lane >> 4, col = lane & 15;
  const int nb = wid * 128;
  f32x4 acc = {0.f, 0.f, 0.f, 0.f};
  float sq = 0.f, sk = 0.f;
#pragma unroll
  for (int k2 = 0; k2 < 4; k2++) {
    int off = nb + k2 * 32 + quad * 8;
    short8_ qf = *(const short8_*)&Qs[col * 520 + off];
    short8_ kf = *(const short8_*)&Ks[col * 520 + off];
#pragma unroll
    for (int j = 0; j < 8; j++) {
      float qv = b2f((u16)qf[j]), kv = b2f((u16)kf[j]);
      sq += qv * qv; sk += kv * kv;
    }
    acc = __builtin_amdgcn_mfma_f32_16x16x32_bf16(qf, kf, acc, 0, 0, 0);
  }

  sq += __shfl_xor(sq, 16); sq += __shfl_xor(sq, 32);
  sk += __shfl_xor(sk, 16); sk += __shfl_xor(sk, 32);
  if (quad == 0) {
    atomicAdd(&qs[b * 128 + h * 16 + col], sq);
    atomicAdd(&ks[b * 128 + h * 16 + col], sk);
  }

  __syncthreads();
  float* Sred = (float*)Qs;
#pragma unroll
  for (int r = 0; r < 4; r++)
    Sred[wid * 256 + (quad * 4 + r) * 16 + col] = acc[r];
  __syncthreads();
  {
    float v = Sred[tid] + Sred[256 + tid] + Sred[512 + tid] + Sred[768 + tid];
    atomicAdd(&S[((size_t)(b * 8 + h) << 8) + tid], v);
  }
}

// ---------------------------------------------------------------------------
// fold Wmv[b] = Mmat[b] (128x128) @ Wbv (128x384); output FRAGMENT-ORDERED.
// ---------------------------------------------------------------------------
__global__ __launch_bounds__(256) void fold_wv(
    const u16* __restrict__ Mmat, const u16* __restrict__ Wbv,
    u16* __restrict__ Wmv)
{
  const int b = blockIdx.y, jb = blockIdx.x;   // grid (12, 8)
  const u16* Mb = Mmat + (size_t)b * 16384;
  const int t = threadIdx.x;
  const int o = t >> 1, jh = t & 1;
  const int j0 = jb * 32 + jh * 16;
  float acc[16];
#pragma unroll
  for (int jj = 0; jj < 16; jj++) acc[jj] = 0.f;
  for (int d = 0; d < 128; d++) {
    float mv = b2f(Mb[o * 128 + d]);
    const u16* wr = Wbv + (size_t)d * 384 + j0;
#pragma unroll
    for (int jj = 0; jj < 16; jj++) acc[jj] += mv * b2f(wr[jj]);
  }
  const int kc = j0 >> 7, ks = (j0 >> 5) & 3, q0 = (j0 >> 3) & 3;
  const int m = o >> 4, col = o & 15;
  u16* outb = Wmv + (size_t)b * 49152;
  const int fi0 = ((kc * 4 + ks) * 8 + m) * 64 + q0 * 16 + col;
  u16x8 v8;
#pragma unroll
  for (int jj = 0; jj < 8; jj++) v8[jj] = f2b(acc[jj]);
  *(u16x8*)&outb[(size_t)fi0 * 8] = v8;
#pragma unroll
  for (int jj = 0; jj < 8; jj++) v8[jj] = f2b(acc[8 + jj]);
  *(u16x8*)&outb[(size_t)(fi0 + 16) * 8] = v8;
}

// ---------------------------------------------------------------------------
// attn = softmax_d( S / (max(|q|,eps)max(|k|,eps)) * T[h] );
// M_b[o][h*16+e] = sum_d w_out[o][h*16+d] attn[h][d][e]
// ---------------------------------------------------------------------------
__global__ __launch_bounds__(256) void attn_mat(
    const float* __restrict__ S, const float* __restrict__ qs,
    const float* __restrict__ ks,
    const void* __restrict__ w_out, const void* __restrict__ temp,
    u16* __restrict__ Mmat, const int* __restrict__ flagp)
{
  const int isbf = *flagp;
  const int b = blockIdx.x;
  __shared__ float attn_s[8 * 16 * 16];
  const int t = threadIdx.x;
  if (t < 128) {
    int h = t >> 4, c = t & 15;
    float qn = fmaxf(sqrtf(fmaxf(qs[b * 128 + h * 16 + c], 0.f)), 1e-12f);
    float tm = ldf(temp, h, isbf);
    float zv[16];
    float m = -1e30f;
    for (int d = 0; d < 16; d++) {
      float kn = fmaxf(sqrtf(fmaxf(ks[b * 128 + h * 16 + d], 0.f)), 1e-12f);
      zv[d] = S[(((size_t)b * 8 + h) * 16 + c) * 16 + d] / (qn * kn) * tm;
      m = fmaxf(m, zv[d]);
    }
    float sum = 0.f;
    for (int d = 0; d < 16; d++) { zv[d] = expf(zv[d] - m); sum += zv[d]; }
    float inv = 1.f / sum;
    for (int d = 0; d < 16; d++) attn_s[(h * 16 + c) * 16 + d] = zv[d] * inv;
  }
  __syncthreads();
  for (int idx = t; idx < 128 * 128; idx += 256) {
    int o = idx >> 7, cp = idx & 127;
    int h = cp >> 4, e = cp & 15;
    float a = 0.f;
    for (int d = 0; d < 16; d++)
      a += ldf(w_out, (size_t)o * 128 + h * 16 + d, isbf) * attn_s[(h * 16 + d) * 16 + e];
    Mmat[(size_t)b * 16384 + idx] = f2b(a);
  }
}

// ---------------------------------------------------------------------------
// Workspace layout (~169.1 MB; >=236 MB proven in r4):
//   xq @ 0: UNIFIED [b][384][NSP] bf16 = 100.7 MB (groups q|k|v)
//   q  @ 100663296 | k @ 134217728 (k = q + 16777216 u16)
//   tail @ 167772160: S(64K) qs(4K) ks(4K) flag(128B) Mmat(256K) Wbv(96K)
//                     Wmv(768K frag-ordered) Wdww(129K f32)
// d_out scratch (u16): Wbqf@0 Wbkf@49152 Wbkvf@98304 — readers finish
// before the final v-pass convgemm writes d_out.
// ---------------------------------------------------------------------------
extern "C" void kernel_launch(void* const* d_in, const int* in_sizes, int n_in,
                              void* d_out, int out_size, void* d_ws, size_t ws_size,
                              hipStream_t stream) {
  const void* x     = d_in[0];
  const void* w_qkv = d_in[1];
  const void* w_dw3 = d_in[2];
  const void* w_dw5 = d_in[3];
  const void* w_dw7 = d_in[4];
  const void* w_q   = d_in[5];
  const void* w_k   = d_in[6];
  const void* w_v   = d_in[7];
  const void* w_o   = d_in[8];
  const void* temp  = d_in[9];

  char* ws = (char*)d_ws;
  u16* dsc = (u16*)d_out;
  u16* Wbqf  = dsc;
  u16* Wbkf  = dsc + 49152;
  u16* Wbkvf = dsc + 98304;

  u16* xq    = (u16*)ws;                     // [b][384][NSP]
  u16* q     = (u16*)(ws + 100663296);
  char* tail = ws + 167772160;
  float* S   = (float*)tail;
  float* qs  = (float*)(tail + 65536);
  float* ks  = (float*)(tail + 69632);
  int* flag  = (int*)(tail + 73728);
  u16* Mmat  = (u16*)(tail + 73856);
  u16* Wbv   = (u16*)(tail + 336000);
  u16* Wmv   = (u16*)(tail + 434304);
  float* Wdww = (float*)(tail + 1220736);
  u16* k     = q + 16777216;

  // all preps + init in one launch
  prep_all<<<462, 256, 0, stream>>>(
      w_q, w_k, w_qkv, w_v, w_dw3, w_dw5, w_dw7, temp,
      Wbqf, Wbkf, Wbkvf, Wbv, Wdww, flag, S);

  // xq (ALL 384 rows of w_qkv) in one dispatch
  gemm_mfma<<<dim3(256, 1, NB), 256, 0, stream>>>(
      Wbkvf, x, xq, 384L * NSP, 384, flag);

  // q + k fused conv+proj in ONE launch (gridDim.y = 2)
  convgemm<<<dim3(256, 2, NB), 256, 0, stream>>>(
      xq, 384L * NSP, 128L * NSP, 0, Wdww,
      Wbqf, 0, 49152, q, 16777216L, 0, flag);

  // S/qs/ks via MFMA
  s_mfma<<<dim3(32, 8, NB), 256, 0, stream>>>(q, k, S, qs, ks);

  attn_mat<<<NB, 256, 0, stream>>>(S, qs, ks, w_o, temp, Mmat, flag);
  fold_wv<<<dim3(12, NB), 256, 0, stream>>>(Mmat, Wbv, Wmv);

  // v: fused conv + (M_b@Wv) -> out (reads group 2 of unified xq)
  convgemm<<<dim3(256, 1, NB), 256, 0, stream>>>(
      xq + 256L * NSP, 384L * NSP, 0, 256, Wdww,
      Wmv, 49152, 0, d_out, 0, 1, flag);
}

// Round 19
// 466.450 us; speedup vs baseline: 1.1313x; 1.0280x over previous
//
#include <hip/hip_runtime.h>
#include <hip/hip_bf16.h>

// Problem constants
#define NB 8
#define NSP 16384      // 128*128

typedef unsigned short u16;
typedef __attribute__((ext_vector_type(8))) short short8_;
typedef __attribute__((ext_vector_type(8))) unsigned short u16x8;
typedef __attribute__((ext_vector_type(4))) float f32x4;
typedef __attribute__((ext_vector_type(4))) unsigned u32x4;

__device__ __forceinline__ float b2f(u16 u) {
  unsigned v = ((unsigned)u) << 16;
  float f;
  __builtin_memcpy(&f, &v, 4);
  return f;
}
__device__ __forceinline__ u16 f2b(float f) {
  __hip_bfloat16 h = __float2bfloat16(f);  // RNE
  u16 u;
  __builtin_memcpy(&u, &h, 2);
  return u;
}
__device__ __forceinline__ float ldf(const void* p, size_t i, int isbf) {
  return isbf ? b2f(((const u16*)p)[i]) : ((const float*)p)[i];
}

// ---------------------------------------------------------------------------
// prep_all: ONE launch replacing all preps (dtype probed per-thread).
// Blocks:   0- 71: zero S/qs/ks (18432 f32) + write flag
//          72-143: fragment-order w_q/w_k/w_qkv (3 mats x 24 blocks)
//         144-335: bf16 copy w_v (49152)
//         336-461: pack dw weights Wdww[384][84] f32
// ---------------------------------------------------------------------------
__global__ __launch_bounds__(256) void prep_all(
    const void* __restrict__ wq, const void* __restrict__ wk,
    const void* __restrict__ wqkv, const void* __restrict__ wv,
    const void* __restrict__ wdw3, const void* __restrict__ wdw5,
    const void* __restrict__ wdw7, const void* __restrict__ temp,
    u16* __restrict__ Wqf, u16* __restrict__ Wkf, u16* __restrict__ Wkvf,
    u16* __restrict__ Wbv, float* __restrict__ Wdww,
    int* __restrict__ flag, float* __restrict__ Sz)
{
  const int isbf = (((const u16*)temp)[0] != 0) ? 1 : 0;
  const int bx = blockIdx.x;
  const int tid = threadIdx.x;

  if (bx < 72) {
    int i = bx * 256 + tid;
    if (i == 0) *flag = isbf;
    if (i < 18432) Sz[i] = 0.f;
  } else if (bx < 144) {
    const int mb = bx - 72;
    const int mat = mb / 24;
    const int fi = (mb - mat * 24) * 256 + tid;   // 0..6143
    const int lane = fi & 63, m = (fi >> 6) & 7, ks = (fi >> 9) & 3, blk = fi >> 11;
    const int quad = lane >> 4, col = lane & 15;
    const void* src;
    u16* dst;
    size_t so;
    if (mat == 2) {
      so = (size_t)(blk * 128 + m * 16 + col) * 128 + ks * 32 + quad * 8;
      src = wqkv; dst = Wkvf;
    } else {
      so = (size_t)(m * 16 + col) * 384 + blk * 128 + ks * 32 + quad * 8;
      src = mat ? wk : wq; dst = mat ? Wkf : Wqf;
    }
    if (isbf) {
      *(u16x8*)&dst[(size_t)fi * 8] = *(const u16x8*)((const u16*)src + so);
    } else {
      f32x4 a = *(const f32x4*)((const float*)src + so);
      f32x4 b = *(const f32x4*)((const float*)src + so + 4);
      u16 us[8];
#pragma unroll
      for (int j = 0; j < 4; j++) { us[j] = f2b(a[j]); us[4 + j] = f2b(b[j]); }
      *(u16x8*)&dst[(size_t)fi * 8] = *(u16x8*)us;
    }
  } else if (bx < 336) {
    int i = (bx - 144) * 256 + tid;               // 0..49151
    Wbv[i] = isbf ? ((const u16*)wv)[i] : f2b(((const float*)wv)[i]);
  } else {
    int i = (bx - 336) * 256 + tid;               // 0..32255
    if (i >= 32256) return;
    int gc = i / 84, t = i - gc * 84;
    float v = 0.f;
    if (t < 9)       v = ldf(wdw3, (size_t)gc * 9 + t, isbf);
    else if (t < 34) v = ldf(wdw5, (size_t)gc * 25 + (t - 9), isbf);
    else if (t < 83) v = ldf(wdw7, (size_t)gc * 49 + (t - 34), isbf);
    Wdww[i] = v;
  }
}

// ---------------------------------------------------------------------------
// MFMA GEMM v5: C[b][o][n] = sum_c A[o][c] * X[b][c][n], K=128, M=384 in one
// dispatch. A fragment-ordered. LDS-transpose epilogue (16B stores).
// ---------------------------------------------------------------------------
__global__ __launch_bounds__(256) void gemm_mfma(
    const u16* __restrict__ Wb,
    const void* __restrict__ X,
    u16* __restrict__ C, long c_bstride, int M,
    const int* __restrict__ flagp)
{
  const int isbf = *flagp;
  __shared__ u16 Xs[128 * 76];    // 19456 B
  __shared__ u16 Cs[128 * 72];    // 18432 B (rows 144B: 16B-aligned)
  const int b = blockIdx.z;
  const int n0 = blockIdx.x * 64;
  const int tid = threadIdx.x;
  const size_t xbase = (size_t)b * 2097152 + n0;  // 128*NSP per batch

  if (isbf) {
    const u16* Xp = (const u16*)X;
#pragma unroll
    for (int i = 0; i < 4; i++) {
      int s = i * 256 + tid;
      int kk = s >> 3, p = (s & 7) * 8;
      u32x4 v = *(const u32x4*)(Xp + xbase + (size_t)kk * NSP + p);
      uint2 lo; lo.x = v[0]; lo.y = v[1];
      uint2 hi; hi.x = v[2]; hi.y = v[3];
      *(uint2*)&Xs[kk * 76 + p]     = lo;
      *(uint2*)&Xs[kk * 76 + p + 4] = hi;
    }
  } else {
    const float* Xp = (const float*)X;
#pragma unroll
    for (int i = 0; i < 4; i++) {
      int s = i * 256 + tid;
      int kk = s >> 3, p = (s & 7) * 8;
      f32x4 fa = *(const f32x4*)(Xp + xbase + (size_t)kk * NSP + p);
      f32x4 fb = *(const f32x4*)(Xp + xbase + (size_t)kk * NSP + p + 4);
      u16 u8v[8];
#pragma unroll
      for (int j = 0; j < 4; j++) u8v[j] = f2b(fa[j]);
#pragma unroll
      for (int j = 0; j < 4; j++) u8v[4 + j] = f2b(fb[j]);
      *(uint2*)&Xs[kk * 76 + p]     = *(uint2*)&u8v[0];
      *(uint2*)&Xs[kk * 76 + p + 4] = *(uint2*)&u8v[4];
    }
  }
  __syncthreads();

  const int wid = tid >> 6, lane = tid & 63;
  const int quad = lane >> 4, col = lane & 15;
  const int nw = wid * 16;
  u16* Cb = C + (size_t)b * c_bstride + n0;
  const short8_* Af = (const short8_*)Wb;

  for (int ob = 0; ob < M; ob += 128) {
    const int obi = ob >> 7;
    f32x4 z = {0.f, 0.f, 0.f, 0.f};
    f32x4 acc[8];
#pragma unroll
    for (int m = 0; m < 8; m++) acc[m] = z;

#pragma unroll
    for (int ks = 0; ks < 4; ks++) {
      const int k0 = ks * 32;
      short8_ bfrag;
#pragma unroll
      for (int j = 0; j < 8; j++)
        bfrag[j] = (short)Xs[(k0 + quad * 8 + j) * 76 + nw + col];
#pragma unroll
      for (int m = 0; m < 8; m++) {
        short8_ afrag = Af[(size_t)(((obi * 4 + ks) * 8 + m) * 64 + lane)];
        acc[m] = __builtin_amdgcn_mfma_f32_16x16x32_bf16(afrag, bfrag, acc[m], 0, 0, 0);
      }
    }

    // epilogue: acc -> Cs (MFMA layout), then coalesced 16B global stores
    if (ob) __syncthreads();           // prev ob's Cs reads done
#pragma unroll
    for (int m = 0; m < 8; m++)
#pragma unroll
      for (int r = 0; r < 4; r++)
        Cs[(m * 16 + quad * 4 + r) * 72 + nw + col] = f2b(acc[m][r]);
    __syncthreads();                   // Cs ready
#pragma unroll
    for (int i = 0; i < 4; i++) {
      int u = i * 256 + tid;           // 0..1023: row=u>>3, off=(u&7)*8
      int row = u >> 3, off = (u & 7) * 8;
      u16x8 v = *(const u16x8*)&Cs[row * 72 + off];
      *(u16x8*)(Cb + (size_t)(ob + row) * NSP + off) = v;
    }
  }
}

// ---------------------------------------------------------------------------
// convgemm v10: barrier-thinned. Bp SEPARATE from in_s (LDS 39.2KB; not the
// limiter) -> 2 barriers/chunk instead of 4 (15 -> 8 per block):
//   B_a: staging(n) visible + MFMA(n-1) done with Bp
//   conv(n) -> write Bp(n) immediately
//   B_b: Bp ready + conv reads done
//   stage in_s/dww(n+1) from prefetch regs  [overlaps MFMA(n)]
//   MFMA(n)
// hreg + wreg prefetched during conv (~112 arch regs, still 3 waves).
// Values / FMA order identical to r16 best. XCD swizzle kept.
// ---------------------------------------------------------------------------
__global__ __launch_bounds__(256) void convgemm(
    const u16* __restrict__ xqg, long x_bstride, long x_gstride, int gc_base0,
    const float* __restrict__ Wdww,
    const u16* __restrict__ Afrag, long a_bstride, long a_gstride,
    void* __restrict__ Out, long out_gstride, int om,
    const int* __restrict__ flagp)
{
  const int isbf = *flagp;
  __shared__ u16 in_s[32 * 240];   // 15360 B
  __shared__ float dww[2688];      // 10752 B
  __shared__ u16 Bp[96 * 68];      // 13056 B
  const int b = blockIdx.z, g = blockIdx.y;
  const int t0 = blockIdx.x;
  const int t = ((t0 & 7) << 5) | (t0 >> 3);   // XCD swizzle: 8 bands of 32 tiles
  const int y0 = (t >> 3) * 4, x0 = (t & 7) * 16;
  const u16* xb = xqg + (size_t)b * x_bstride + (size_t)g * x_gstride;
  const short8_* Af = (const short8_*)(Afrag + (size_t)b * a_bstride + (size_t)g * a_gstride);
  const int gc_base = gc_base0 + g * 128;
  const int tid = threadIdx.x;
  const int cc_t = tid >> 3;
  const int py_t = (tid >> 1) & 3;
  const int xh   = tid & 1;
  const int wid = tid >> 6, lane = tid & 63;
  const int quad = lane >> 4, col = lane & 15;

  // ---- hoisted staging geometry (invariant across chunks and i) ----
  const int hy  = lane / 6;
  const int hc4 = lane - hy * 6;
  const int gy_s = y0 - 3 + hy, gx_s = x0 - 4 + hc4 * 4;
  const bool sval = (lane < 60);
  const bool gok = sval && ((unsigned)gy_s < 128u) && ((unsigned)gx_s <= 124u);
  const u16* gsrc0 = xb + (size_t)wid * NSP + (gy_s * 128 + gx_s);  // +(c0+i*4)*NSP
  const int ldso = wid * 240 + hy * 24 + hc4 * 4;                   // +i*960

  uint2 hreg[8];
  f32x4 wreg[3];

  // ---- prologue: chunk 0 halo + weights -> regs -> LDS (B_a covers) ----
#pragma unroll
  for (int i = 0; i < 8; i++) {
    uint2 v; v.x = 0u; v.y = 0u;
    if (gok) v = *(const uint2*)(gsrc0 + (size_t)(i * 4) * NSP);
    hreg[i] = v;
  }
  {
    const float* wg = Wdww + (size_t)gc_base * 84;
#pragma unroll
    for (int i = 0; i < 3; i++) {
      int s = i * 256 + tid;
      f32x4 wv = {0.f, 0.f, 0.f, 0.f};
      if (s < 672) wv = *(const f32x4*)(wg + s * 4);
      wreg[i] = wv;
    }
  }
  if (sval) {
#pragma unroll
    for (int i = 0; i < 8; i++)
      *(uint2*)&in_s[ldso + i * 960] = hreg[i];
  }
#pragma unroll
  for (int i = 0; i < 3; i++) {
    int s = i * 256 + tid;
    if (s < 672) *(f32x4*)&dww[s * 4] = wreg[i];
  }

  f32x4 z = {0.f, 0.f, 0.f, 0.f};
  f32x4 acc[8];
#pragma unroll
  for (int m = 0; m < 8; m++) acc[m] = z;

  for (int chn = 0; chn < 4; chn++) {
    const int c0 = chn * 32;
    __syncthreads();            // B_a: staging(chn) visible; MFMA(chn-1) done

    // prefetch next chunk halo + weights into regs (hides under conv)
    if (chn < 3) {
      const u16* gsrc = gsrc0 + (size_t)(c0 + 32) * NSP;
#pragma unroll
      for (int i = 0; i < 8; i++) {
        uint2 v; v.x = 0u; v.y = 0u;
        if (gok) v = *(const uint2*)(gsrc + (size_t)(i * 4) * NSP);
        hreg[i] = v;
      }
      const float* wg = Wdww + (size_t)(gc_base + c0 + 32) * 84;
#pragma unroll
      for (int i = 0; i < 3; i++) {
        int s = i * 256 + tid;
        f32x4 wv = {0.f, 0.f, 0.f, 0.f};
        if (s < 672) wv = *(const f32x4*)(wg + s * 4);
        wreg[i] = wv;
      }
    }

    // --- conv: 3 scales, 8 px per thread -> registers ---
    float a0[8], a1[8], a2[8];
#pragma unroll
    for (int px = 0; px < 8; px++) { a0[px] = 0.f; a1[px] = 0.f; a2[px] = 0.f; }
    {
      const float* dwc = dww + cc_t * 84;
      const u16* rowbase = in_s + cc_t * 240 + xh * 8;
#pragma unroll
      for (int dy = 0; dy < 7; dy++) {
        const u16* rp = rowbase + (py_t + dy) * 24;
        u32x4 ra = *(const u32x4*)rp;
        u32x4 rb = *(const u32x4*)(rp + 8);
        float row[14];
#pragma unroll
        for (int j = 0; j < 14; j++) {
          int l = j + 1;
          unsigned wd = (l < 8) ? ra[l >> 1] : rb[(l >> 1) - 4];
          unsigned bits = (l & 1) ? (wd & 0xffff0000u) : (wd << 16);
          __builtin_memcpy(&row[j], &bits, 4);
        }
#pragma unroll
        for (int dx = 0; dx < 7; dx++) {
          float wv = dwc[34 + dy * 7 + dx];
#pragma unroll
          for (int px = 0; px < 8; px++) a2[px] += row[px + dx] * wv;
        }
        if (dy >= 1 && dy <= 5) {
          int dy5 = dy - 1;
#pragma unroll
          for (int dx = 0; dx < 5; dx++) {
            float wv = dwc[9 + dy5 * 5 + dx];
#pragma unroll
            for (int px = 0; px < 8; px++) a1[px] += row[px + 1 + dx] * wv;
          }
        }
        if (dy >= 2 && dy <= 4) {
          int dy3 = dy - 2;
#pragma unroll
          for (int dx = 0; dx < 3; dx++) {
            float wv = dwc[dy3 * 3 + dx];
#pragma unroll
            for (int px = 0; px < 8; px++) a0[px] += row[px + 2 + dx] * wv;
          }
        }
      }
    }

    // write Bp immediately (separate buffer; B_a guarded prev MFMA)
    {
      const int pb = py_t * 16 + xh * 8;
      u16 us[8];
#pragma unroll
      for (int px = 0; px < 8; px++) us[px] = f2b(a0[px]);
      *(uint2*)&Bp[(0 * 32 + cc_t) * 68 + pb]     = *(uint2*)&us[0];
      *(uint2*)&Bp[(0 * 32 + cc_t) * 68 + pb + 4] = *(uint2*)&us[4];
#pragma unroll
      for (int px = 0; px < 8; px++) us[px] = f2b(a1[px]);
      *(uint2*)&Bp[(1 * 32 + cc_t) * 68 + pb]     = *(uint2*)&us[0];
      *(uint2*)&Bp[(1 * 32 + cc_t) * 68 + pb + 4] = *(uint2*)&us[4];
#pragma unroll
      for (int px = 0; px < 8; px++) us[px] = f2b(a2[px]);
      *(uint2*)&Bp[(2 * 32 + cc_t) * 68 + pb]     = *(uint2*)&us[0];
      *(uint2*)&Bp[(2 * 32 + cc_t) * 68 + pb + 4] = *(uint2*)&us[4];
    }
    __syncthreads();            // B_b: Bp ready; conv in_s/dww reads done

    // stage next chunk into LDS (overlaps with MFMA below; disjoint bufs)
    if (chn < 3) {
      if (sval) {
#pragma unroll
        for (int i = 0; i < 8; i++)
          *(uint2*)&in_s[ldso + i * 960] = hreg[i];
      }
#pragma unroll
      for (int i = 0; i < 3; i++) {
        int s = i * 256 + tid;
        if (s < 672) *(f32x4*)&dww[s * 4] = wreg[i];
      }
    }

    // --- MFMA accumulate: K-slices (s=scale -> kc, chn -> ks) ---
#pragma unroll
    for (int s = 0; s < 3; s++) {
      const int k0 = s * 32;
      short8_ bfrag;
#pragma unroll
      for (int j = 0; j < 8; j++)
        bfrag[j] = (short)Bp[(k0 + quad * 8 + j) * 68 + wid * 16 + col];
#pragma unroll
      for (int m = 0; m < 8; m++) {
        short8_ afrag = Af[(size_t)(((s * 4 + chn) * 8 + m) * 64 + lane)];
        acc[m] = __builtin_amdgcn_mfma_f32_16x16x32_bf16(afrag, bfrag, acc[m], 0, 0, 0);
      }
    }
  }

  // epilogue
#pragma unroll
  for (int m = 0; m < 8; m++)
#pragma unroll
    for (int r = 0; r < 4; r++) {
      int o = m * 16 + quad * 4 + r;
      int ng = (y0 + wid) * 128 + x0 + col;
      size_t base = ((size_t)b * 128 + o) * NSP + ng;
      if (om && !isbf) ((float*)Out)[base] = acc[m][r];
      else ((u16*)Out + (size_t)g * out_gstride)[base] = f2b(acc[m][r]);
    }
}

// ---------------------------------------------------------------------------
// s_mfma: S[b][h] (16x16) = q_h · k_h^T via MFMA + fused qs/ks norms.
// ---------------------------------------------------------------------------
__global__ __launch_bounds__(256) void s_mfma(
    const u16* __restrict__ qb, const u16* __restrict__ kb,
    float* __restrict__ S, float* __restrict__ qs, float* __restrict__ ks)
{
  __shared__ u16 Qs[16 * 520];   // 16640 B
  __shared__ u16 Ks[16 * 520];   // 16640 B
  const int chunk = blockIdx.x, h = blockIdx.y, b = blockIdx.z;
  const int tid = threadIdx.x;
  const int n0 = chunk * 512;
  const size_t gbase = ((size_t)b * 128 + h * 16) * NSP + n0;

#pragma unroll
  for (int i = 0; i < 4; i++) {
    int idx = i * 256 + tid;            // 0..1023
    int row = idx >> 6, off = (idx & 63) * 8;
    *(u16x8*)&Qs[row * 520 + off] = *(const u16x8*)(qb + gbase + (size_t)row * NSP + off);
    *(u16x8*)&Ks[row * 520 + off] = *(const u16x8*)(kb + gbase + (size_t)row * NSP + off);
  }
  __syncthreads();

  const int wid = tid >> 6, lane = tid & 63;
  const int quad = lane >> 4, col = lane & 15;
  const int nb = wid * 128;
  f32x4 acc = {0.f, 0.f, 0.f, 0.f};
  float sq = 0.f, sk = 0.f;
#pragma unroll
  for (int k2 = 0; k2 < 4; k2++) {
    int off = nb + k2 * 32 + quad * 8;
    short8_ qf = *(const short8_*)&Qs[col * 520 + off];
    short8_ kf = *(const short8_*)&Ks[col * 520 + off];
#pragma unroll
    for (int j = 0; j < 8; j++) {
      float qv = b2f((u16)qf[j]), kv = b2f((u16)kf[j]);
      sq += qv * qv; sk += kv * kv;
    }
    acc = __builtin_amdgcn_mfma_f32_16x16x32_bf16(qf, kf, acc, 0, 0, 0);
  }

  sq += __shfl_xor(sq, 16); sq += __shfl_xor(sq, 32);
  sk += __shfl_xor(sk, 16); sk += __shfl_xor(sk, 32);
  if (quad == 0) {
    atomicAdd(&qs[b * 128 + h * 16 + col], sq);
    atomicAdd(&ks[b * 128 + h * 16 + col], sk);
  }

  __syncthreads();
  float* Sred = (float*)Qs;
#pragma unroll
  for (int r = 0; r < 4; r++)
    Sred[wid * 256 + (quad * 4 + r) * 16 + col] = acc[r];
  __syncthreads();
  {
    float v = Sred[tid] + Sred[256 + tid] + Sred[512 + tid] + Sred[768 + tid];
    atomicAdd(&S[((size_t)(b * 8 + h) << 8) + tid], v);
  }
}

// ---------------------------------------------------------------------------
// fold Wmv[b] = Mmat[b] (128x128) @ Wbv (128x384); output FRAGMENT-ORDERED.
// ---------------------------------------------------------------------------
__global__ __launch_bounds__(256) void fold_wv(
    const u16* __restrict__ Mmat, const u16* __restrict__ Wbv,
    u16* __restrict__ Wmv)
{
  const int b = blockIdx.y, jb = blockIdx.x;   // grid (12, 8)
  const u16* Mb = Mmat + (size_t)b * 16384;
  const int t = threadIdx.x;
  const int o = t >> 1, jh = t & 1;
  const int j0 = jb * 32 + jh * 16;
  float acc[16];
#pragma unroll
  for (int jj = 0; jj < 16; jj++) acc[jj] = 0.f;
  for (int d = 0; d < 128; d++) {
    float mv = b2f(Mb[o * 128 + d]);
    const u16* wr = Wbv + (size_t)d * 384 + j0;
#pragma unroll
    for (int jj = 0; jj < 16; jj++) acc[jj] += mv * b2f(wr[jj]);
  }
  const int kc = j0 >> 7, ks = (j0 >> 5) & 3, q0 = (j0 >> 3) & 3;
  const int m = o >> 4, col = o & 15;
  u16* outb = Wmv + (size_t)b * 49152;
  const int fi0 = ((kc * 4 + ks) * 8 + m) * 64 + q0 * 16 + col;
  u16x8 v8;
#pragma unroll
  for (int jj = 0; jj < 8; jj++) v8[jj] = f2b(acc[jj]);
  *(u16x8*)&outb[(size_t)fi0 * 8] = v8;
#pragma unroll
  for (int jj = 0; jj < 8; jj++) v8[jj] = f2b(acc[8 + jj]);
  *(u16x8*)&outb[(size_t)(fi0 + 16) * 8] = v8;
}

// ---------------------------------------------------------------------------
// attn = softmax_d( S / (max(|q|,eps)max(|k|,eps)) * T[h] );
// M_b[o][h*16+e] = sum_d w_out[o][h*16+d] attn[h][d][e]
// ---------------------------------------------------------------------------
__global__ __launch_bounds__(256) void attn_mat(
    const float* __restrict__ S, const float* __restrict__ qs,
    const float* __restrict__ ks,
    const void* __restrict__ w_out, const void* __restrict__ temp,
    u16* __restrict__ Mmat, const int* __restrict__ flagp)
{
  const int isbf = *flagp;
  const int b = blockIdx.x;
  __shared__ float attn_s[8 * 16 * 16];
  const int t = threadIdx.x;
  if (t < 128) {
    int h = t >> 4, c = t & 15;
    float qn = fmaxf(sqrtf(fmaxf(qs[b * 128 + h * 16 + c], 0.f)), 1e-12f);
    float tm = ldf(temp, h, isbf);
    float zv[16];
    float m = -1e30f;
    for (int d = 0; d < 16; d++) {
      float kn = fmaxf(sqrtf(fmaxf(ks[b * 128 + h * 16 + d], 0.f)), 1e-12f);
      zv[d] = S[(((size_t)b * 8 + h) * 16 + c) * 16 + d] / (qn * kn) * tm;
      m = fmaxf(m, zv[d]);
    }
    float sum = 0.f;
    for (int d = 0; d < 16; d++) { zv[d] = expf(zv[d] - m); sum += zv[d]; }
    float inv = 1.f / sum;
    for (int d = 0; d < 16; d++) attn_s[(h * 16 + c) * 16 + d] = zv[d] * inv;
  }
  __syncthreads();
  for (int idx = t; idx < 128 * 128; idx += 256) {
    int o = idx >> 7, cp = idx & 127;
    int h = cp >> 4, e = cp & 15;
    float a = 0.f;
    for (int d = 0; d < 16; d++)
      a += ldf(w_out, (size_t)o * 128 + h * 16 + d, isbf) * attn_s[(h * 16 + d) * 16 + e];
    Mmat[(size_t)b * 16384 + idx] = f2b(a);
  }
}

// ---------------------------------------------------------------------------
// Workspace layout (~169.1 MB; >=236 MB proven in r4):
//   xq @ 0: UNIFIED [b][384][NSP] bf16 = 100.7 MB (groups q|k|v)
//   q  @ 100663296 | k @ 134217728 (k = q + 16777216 u16)
//   tail @ 167772160: S(64K) qs(4K) ks(4K) flag(128B) Mmat(256K) Wbv(96K)
//                     Wmv(768K frag-ordered) Wdww(129K f32)
// d_out scratch (u16): Wbqf@0 Wbkf@49152 Wbkvf@98304 — readers finish
// before the final v-pass convgemm writes d_out.
// ---------------------------------------------------------------------------
extern "C" void kernel_launch(void* const* d_in, const int* in_sizes, int n_in,
                              void* d_out, int out_size, void* d_ws, size_t ws_size,
                              hipStream_t stream) {
  const void* x     = d_in[0];
  const void* w_qkv = d_in[1];
  const void* w_dw3 = d_in[2];
  const void* w_dw5 = d_in[3];
  const void* w_dw7 = d_in[4];
  const void* w_q   = d_in[5];
  const void* w_k   = d_in[6];
  const void* w_v   = d_in[7];
  const void* w_o   = d_in[8];
  const void* temp  = d_in[9];

  char* ws = (char*)d_ws;
  u16* dsc = (u16*)d_out;
  u16* Wbqf  = dsc;
  u16* Wbkf  = dsc + 49152;
  u16* Wbkvf = dsc + 98304;

  u16* xq    = (u16*)ws;                     // [b][384][NSP]
  u16* q     = (u16*)(ws + 100663296);
  char* tail = ws + 167772160;
  float* S   = (float*)tail;
  float* qs  = (float*)(tail + 65536);
  float* ks  = (float*)(tail + 69632);
  int* flag  = (int*)(tail + 73728);
  u16* Mmat  = (u16*)(tail + 73856);
  u16* Wbv   = (u16*)(tail + 336000);
  u16* Wmv   = (u16*)(tail + 434304);
  float* Wdww = (float*)(tail + 1220736);
  u16* k     = q + 16777216;

  // all preps + init in one launch
  prep_all<<<462, 256, 0, stream>>>(
      w_q, w_k, w_qkv, w_v, w_dw3, w_dw5, w_dw7, temp,
      Wbqf, Wbkf, Wbkvf, Wbv, Wdww, flag, S);

  // xq (ALL 384 rows of w_qkv) in one dispatch
  gemm_mfma<<<dim3(256, 1, NB), 256, 0, stream>>>(
      Wbkvf, x, xq, 384L * NSP, 384, flag);

  // q + k fused conv+proj in ONE launch (gridDim.y = 2)
  convgemm<<<dim3(256, 2, NB), 256, 0, stream>>>(
      xq, 384L * NSP, 128L * NSP, 0, Wdww,
      Wbqf, 0, 49152, q, 16777216L, 0, flag);

  // S/qs/ks via MFMA
  s_mfma<<<dim3(32, 8, NB), 256, 0, stream>>>(q, k, S, qs, ks);

  attn_mat<<<NB, 256, 0, stream>>>(S, qs, ks, w_o, temp, Mmat, flag);
  fold_wv<<<dim3(12, NB), 256, 0, stream>>>(Mmat, Wbv, Wmv);

  // v: fused conv + (M_b@Wv) -> out (reads group 2 of unified xq)
  convgemm<<<dim3(256, 1, NB), 256, 0, stream>>>(
      xq + 256L * NSP, 384L * NSP, 0, 256, Wdww,
      Wmv, 49152, 0, d_out, 0, 1, flag);
}